// Round 1
// baseline (1189.830 us; speedup 1.0000x reference)
//
#include <hip/hip_runtime.h>
#include <math.h>

#define N_NODES 100000
#define N_EDGES 1200000
#define DD 64
#define HH 4096
#define H3 12288

// ---------------- zero fill (float4) ----------------
__global__ void zero_kernel(float4* __restrict__ p, int n4) {
    int i = blockIdx.x * blockDim.x + threadIdx.x;
    if (i < n4) p[i] = make_float4(0.f, 0.f, 0.f, 0.f);
}

// ---------------- degrees ----------------
__global__ void deg_kernel(const int* __restrict__ src, const int* __restrict__ dst,
                           float* __restrict__ dout, float* __restrict__ din) {
    int i = blockIdx.x * blockDim.x + threadIdx.x;
    int stride = gridDim.x * blockDim.x;
    for (int e = i; e < N_EDGES; e += stride) {
        atomicAdd(&dout[src[e]], 1.0f);
        atomicAdd(&din[dst[e]], 1.0f);
    }
}

__global__ void rsqrt_kernel(float* __restrict__ a, int n) {
    int i = blockIdx.x * blockDim.x + threadIdx.x;
    if (i < n) a[i] = rsqrtf(fmaxf(a[i], 1.0f));
}

// ---------------- GRU matvecs ----------------
// wave-task t in [0, 24576): mat = t/12288 (0: w_ih, 1: w_hh), row = t%12288.
// Each wave reads the 16KB row ONCE and dots it with both layers' vectors.
// gbuf layout: [0]=w_ih@gc1_hist, [1]=w_ih@gc2_hist, [2]=w_hh@gc1_w, [3]=w_hh@gc2_w
__global__ __launch_bounds__(256) void gru_matvec(
        const float* __restrict__ w_ih, const float* __restrict__ w_hh,
        const float* __restrict__ x1, const float* __restrict__ x2,
        const float* __restrict__ h1, const float* __restrict__ h2,
        float* __restrict__ gbuf) {
    int wave = (blockIdx.x * blockDim.x + threadIdx.x) >> 6;
    int lane = threadIdx.x & 63;
    int mat  = wave / H3;
    int row  = wave - mat * H3;
    const float4* M  = (const float4*)((mat ? w_hh : w_ih) + (size_t)row * HH);
    const float4* va = (const float4*)(mat ? h1 : x1);
    const float4* vb = (const float4*)(mat ? h2 : x2);
    float acc_a = 0.f, acc_b = 0.f;
#pragma unroll
    for (int i = 0; i < 16; ++i) {
        float4 m = M[lane + i * 64];
        float4 a = va[lane + i * 64];
        float4 b = vb[lane + i * 64];
        acc_a += m.x * a.x + m.y * a.y + m.z * a.z + m.w * a.w;
        acc_b += m.x * b.x + m.y * b.y + m.z * b.z + m.w * b.w;
    }
#pragma unroll
    for (int off = 32; off > 0; off >>= 1) {
        acc_a += __shfl_xor(acc_a, off);
        acc_b += __shfl_xor(acc_b, off);
    }
    if (lane == 0) {
        gbuf[(mat * 2 + 0) * H3 + row] = acc_a;
        gbuf[(mat * 2 + 1) * H3 + row] = acc_b;
    }
}

// ---------------- GRU gate combine ----------------
__global__ void gru_combine(const float* __restrict__ gbuf,
                            const float* __restrict__ b_ih, const float* __restrict__ b_hh,
                            const float* __restrict__ w1_cur, const float* __restrict__ w2_cur,
                            float* __restrict__ wevo) {
    int j = blockIdx.x * blockDim.x + threadIdx.x;  // [0, 8192)
    if (j >= 2 * HH) return;
    int layer = j >> 12;
    int jj = j & (HH - 1);
    const float* gx = gbuf + layer * H3;
    const float* gh = gbuf + (2 + layer) * H3;
    float xr = gx[jj] + b_ih[jj];
    float xz = gx[HH + jj] + b_ih[HH + jj];
    float xn = gx[2 * HH + jj] + b_ih[2 * HH + jj];
    float hr = gh[jj] + b_hh[jj];
    float hz = gh[HH + jj] + b_hh[HH + jj];
    float hn = gh[2 * HH + jj] + b_hh[2 * HH + jj];
    float h = (layer ? w2_cur : w1_cur)[jj];
    float r = 1.0f / (1.0f + expf(-(xr + hr)));
    float z = 1.0f / (1.0f + expf(-(xz + hz)));
    float n = tanhf(xn + r * hn);
    wevo[layer * HH + jj] = (1.0f - z) * n + z * h;
}

// ---------------- node GEMM: out[r][:] = pre(in[r][:]) @ w ----------------
// mode 0: v = in * rs_out[r]                      (conv1 input scaling)
// mode 1: v = relu(in * rs_in[r] + bias) * rs_out[r]  (conv1 finalize + relu + conv2 scaling)
__global__ __launch_bounds__(256) void gemm64(
        const float* __restrict__ in, const float* __restrict__ w,
        float* __restrict__ out, const float* __restrict__ rs_out,
        const float* __restrict__ rs_in, const float* __restrict__ bias, int mode) {
    __shared__ float wl[HH];
    __shared__ float xs[4][DD];
    for (int i = threadIdx.x; i < HH; i += 256) wl[i] = w[i];
    __syncthreads();
    int wv = threadIdx.x >> 6, lane = threadIdx.x & 63;
    int r = blockIdx.x * 4 + wv;          // grid = 25000 exactly covers 100000
    float v = in[(size_t)r * DD + lane];
    if (mode) v = fmaxf(fmaf(v, rs_in[r], bias[lane]), 0.0f);
    v *= rs_out[r];
    xs[wv][lane] = v;
    __syncthreads();
    float acc = 0.f;
#pragma unroll
    for (int k = 0; k < DD; ++k) acc = fmaf(xs[wv][k], wl[k * DD + lane], acc);
    out[(size_t)r * DD + lane] = acc;
}

// ---------------- edge gather + atomic scatter ----------------
__global__ __launch_bounds__(256) void scatter_kernel(
        const float* __restrict__ h, const int* __restrict__ src,
        const int* __restrict__ dst, float* __restrict__ agg) {
    int gw = (blockIdx.x * blockDim.x + threadIdx.x) >> 6;
    int lane = threadIdx.x & 63;
    int nw = (gridDim.x * blockDim.x) >> 6;
    for (int e = gw; e < N_EDGES; e += nw) {
        int s = src[e], d = dst[e];
        float v = h[(size_t)s * DD + lane];
        atomicAdd(&agg[(size_t)d * DD + lane], v);
    }
}

// ---------------- final: out = agg * rs_in + bias ----------------
__global__ void final_kernel(const float4* __restrict__ agg, const float* __restrict__ rs_in,
                             const float4* __restrict__ bias, float4* __restrict__ out) {
    int i = blockIdx.x * blockDim.x + threadIdx.x;  // per float4
    if (i >= N_NODES * 16) return;
    int r = i >> 4;
    int c4 = i & 15;
    float4 a = agg[i];
    float4 b = bias[c4];
    float s = rs_in[r];
    float4 o;
    o.x = fmaf(a.x, s, b.x);
    o.y = fmaf(a.y, s, b.y);
    o.z = fmaf(a.z, s, b.z);
    o.w = fmaf(a.w, s, b.w);
    out[i] = o;
}

extern "C" void kernel_launch(void* const* d_in, const int* in_sizes, int n_in,
                              void* d_out, int out_size, void* d_ws, size_t ws_size,
                              hipStream_t stream) {
    const float* node_emb   = (const float*)d_in[0];
    const int*   src        = (const int*)d_in[1];
    const int*   dst        = (const int*)d_in[2];
    const float* gc1_weight = (const float*)d_in[3];
    const float* gc1_bias   = (const float*)d_in[4];
    const float* gc2_weight = (const float*)d_in[5];
    const float* gc2_bias   = (const float*)d_in[6];
    const float* gc1_hist   = (const float*)d_in[7];
    const float* gc2_hist   = (const float*)d_in[8];
    const float* w_ih       = (const float*)d_in[9];
    const float* w_hh       = (const float*)d_in[10];
    const float* b_ih       = (const float*)d_in[11];
    const float* b_hh       = (const float*)d_in[12];
    float* out = (float*)d_out;

    float* ws     = (float*)d_ws;
    float* rs_out = ws;                    // N_NODES
    float* rs_in  = ws + N_NODES;          // N_NODES
    float* gbuf   = ws + 2 * N_NODES;      // 4*H3 = 49152
    float* wevo   = gbuf + 4 * H3;         // 2*HH = 8192 (w1, then w2)
    float* agg    = wevo + 2 * HH;         // N_NODES*DD = 6.4M floats

    // degrees (shared by both convs)
    zero_kernel<<<(2 * N_NODES / 4 + 255) / 256, 256, 0, stream>>>((float4*)rs_out, 2 * N_NODES / 4);
    deg_kernel<<<2048, 256, 0, stream>>>(src, dst, rs_out, rs_in);
    rsqrt_kernel<<<(2 * N_NODES + 255) / 256, 256, 0, stream>>>(rs_out, 2 * N_NODES);

    // weight evolution (two GRU cells fused: shared w_ih/w_hh read)
    gru_matvec<<<6144, 256, 0, stream>>>(w_ih, w_hh, gc1_hist, gc2_hist,
                                         gc1_weight, gc2_weight, gbuf);
    gru_combine<<<32, 256, 0, stream>>>(gbuf, b_ih, b_hh, gc1_weight, gc2_weight, wevo);

    // conv1: h = (x * rs_out) @ w1   (h staged in d_out)
    gemm64<<<25000, 256, 0, stream>>>(node_emb, wevo, out, rs_out, rs_in, gc1_bias, 0);
    zero_kernel<<<(N_NODES * DD / 4 + 255) / 256, 256, 0, stream>>>((float4*)agg, N_NODES * DD / 4);
    scatter_kernel<<<4096, 256, 0, stream>>>(out, src, dst, agg);

    // conv2 input: relu(agg * rs_in + b1) * rs_out, then @ w2 (back into d_out)
    gemm64<<<25000, 256, 0, stream>>>(agg, wevo + HH, out, rs_out, rs_in, gc1_bias, 1);
    zero_kernel<<<(N_NODES * DD / 4 + 255) / 256, 256, 0, stream>>>((float4*)agg, N_NODES * DD / 4);
    scatter_kernel<<<4096, 256, 0, stream>>>(out, src, dst, agg);

    // final: out = agg * rs_in + b2
    final_kernel<<<(N_NODES * 16 + 255) / 256, 256, 0, stream>>>(
        (const float4*)agg, rs_in, (const float4*)gc2_bias, (float4*)out);
}

// Round 2
// 886.917 us; speedup vs baseline: 1.3415x; 1.3415x over previous
//
#include <hip/hip_runtime.h>
#include <math.h>

#define N_NODES 100000
#define N_EDGES 1200000
#define DD 64
#define HH 4096
#define H3 12288
#define NB_SCAN 98  // ceil(100000/1024)

// ---------------- zero fill (int4) ----------------
__global__ void zero_i4(int4* __restrict__ p, int n4) {
    int i = blockIdx.x * blockDim.x + threadIdx.x;
    if (i < n4) p[i] = make_int4(0, 0, 0, 0);
}

// ---------------- degree histograms (int atomics, L2-resident) ----------------
__global__ void hist_kernel(const int* __restrict__ src, const int* __restrict__ dst,
                            int* __restrict__ hs, int* __restrict__ hd) {
    int i = blockIdx.x * blockDim.x + threadIdx.x;
    int stride = gridDim.x * blockDim.x;
    for (int e = i; e < N_EDGES; e += stride) {
        atomicAdd(&hs[src[e]], 1);
        atomicAdd(&hd[dst[e]], 1);
    }
}

__global__ void rsqrt_from_hist(const int* __restrict__ hs, const int* __restrict__ hd,
                                float* __restrict__ rs_out, float* __restrict__ rs_in) {
    int i = blockIdx.x * blockDim.x + threadIdx.x;
    if (i < N_NODES) {
        rs_out[i] = rsqrtf(fmaxf((float)hs[i], 1.0f));
        rs_in[i]  = rsqrtf(fmaxf((float)hd[i], 1.0f));
    }
}

// ---------------- exclusive scan of hist_dst -> offsets ----------------
__global__ __launch_bounds__(256) void scan1(const int* __restrict__ hist, int* __restrict__ offs,
                                             int* __restrict__ bsum) {
    __shared__ int wsum[4];
    int b = blockIdx.x;
    int base = b * 1024;
    int t = threadIdx.x;
    int idx = base + t * 4;
    int v0 = 0, v1 = 0, v2 = 0, v3 = 0;
    if (idx + 0 < N_NODES) v0 = hist[idx + 0];
    if (idx + 1 < N_NODES) v1 = hist[idx + 1];
    if (idx + 2 < N_NODES) v2 = hist[idx + 2];
    if (idx + 3 < N_NODES) v3 = hist[idx + 3];
    int s = v0 + v1 + v2 + v3;
    int lane = t & 63, wv = t >> 6;
    int sc = s;
#pragma unroll
    for (int off = 1; off < 64; off <<= 1) {
        int n = __shfl_up(sc, off);
        if (lane >= off) sc += n;
    }
    if (lane == 63) wsum[wv] = sc;
    __syncthreads();
    int wadd = 0;
    for (int i = 0; i < wv; ++i) wadd += wsum[i];
    int excl = wadd + sc - s;  // exclusive prefix within block for this thread's 4 elems
    if (idx + 0 < N_NODES) offs[idx + 0] = excl;
    if (idx + 1 < N_NODES) offs[idx + 1] = excl + v0;
    if (idx + 2 < N_NODES) offs[idx + 2] = excl + v0 + v1;
    if (idx + 3 < N_NODES) offs[idx + 3] = excl + v0 + v1 + v2;
    if (t == 255) bsum[b] = wadd + sc;  // block total
}

__global__ void scan2(int* __restrict__ bsum) {
    if (threadIdx.x == 0 && blockIdx.x == 0) {
        int acc = 0;
        for (int i = 0; i < NB_SCAN; ++i) { int v = bsum[i]; bsum[i] = acc; acc += v; }
    }
}

__global__ void scan3(int* __restrict__ offs, const int* __restrict__ bsum,
                      int* __restrict__ cursor) {
    int i = blockIdx.x * blockDim.x + threadIdx.x;
    if (i < N_NODES) {
        int o = offs[i] + bsum[i >> 10];
        offs[i] = o;
        cursor[i] = o;
    } else if (i == N_NODES) {
        offs[N_NODES] = N_EDGES;
    }
}

// ---------------- reorder edges by dst (counting sort payload pass) ----------------
__global__ void reorder_kernel(const int* __restrict__ src, const int* __restrict__ dst,
                               int* __restrict__ cursor, int* __restrict__ ssort) {
    int e = blockIdx.x * blockDim.x + threadIdx.x;
    if (e < N_EDGES) {
        int d = dst[e];
        int p = atomicAdd(&cursor[d], 1);
        ssort[p] = src[e];
    }
}

// ---------------- GRU matvecs ----------------
// wave-task t in [0, 24576): mat = t/12288 (0: w_ih, 1: w_hh), row = t%12288.
// Each wave reads the 16KB row ONCE and dots it with both layers' vectors.
// gbuf layout: [0]=w_ih@gc1_hist, [1]=w_ih@gc2_hist, [2]=w_hh@gc1_w, [3]=w_hh@gc2_w
__global__ __launch_bounds__(256) void gru_matvec(
        const float* __restrict__ w_ih, const float* __restrict__ w_hh,
        const float* __restrict__ x1, const float* __restrict__ x2,
        const float* __restrict__ h1, const float* __restrict__ h2,
        float* __restrict__ gbuf) {
    int wave = (blockIdx.x * blockDim.x + threadIdx.x) >> 6;
    int lane = threadIdx.x & 63;
    int mat  = wave / H3;
    int row  = wave - mat * H3;
    const float4* M  = (const float4*)((mat ? w_hh : w_ih) + (size_t)row * HH);
    const float4* va = (const float4*)(mat ? h1 : x1);
    const float4* vb = (const float4*)(mat ? h2 : x2);
    float acc_a = 0.f, acc_b = 0.f;
#pragma unroll
    for (int i = 0; i < 16; ++i) {
        float4 m = M[lane + i * 64];
        float4 a = va[lane + i * 64];
        float4 b = vb[lane + i * 64];
        acc_a += m.x * a.x + m.y * a.y + m.z * a.z + m.w * a.w;
        acc_b += m.x * b.x + m.y * b.y + m.z * b.z + m.w * b.w;
    }
#pragma unroll
    for (int off = 32; off > 0; off >>= 1) {
        acc_a += __shfl_xor(acc_a, off);
        acc_b += __shfl_xor(acc_b, off);
    }
    if (lane == 0) {
        gbuf[(mat * 2 + 0) * H3 + row] = acc_a;
        gbuf[(mat * 2 + 1) * H3 + row] = acc_b;
    }
}

// ---------------- GRU gate combine ----------------
__global__ void gru_combine(const float* __restrict__ gbuf,
                            const float* __restrict__ b_ih, const float* __restrict__ b_hh,
                            const float* __restrict__ w1_cur, const float* __restrict__ w2_cur,
                            float* __restrict__ wevo) {
    int j = blockIdx.x * blockDim.x + threadIdx.x;  // [0, 8192)
    if (j >= 2 * HH) return;
    int layer = j >> 12;
    int jj = j & (HH - 1);
    const float* gx = gbuf + layer * H3;
    const float* gh = gbuf + (2 + layer) * H3;
    float xr = gx[jj] + b_ih[jj];
    float xz = gx[HH + jj] + b_ih[HH + jj];
    float xn = gx[2 * HH + jj] + b_ih[2 * HH + jj];
    float hr = gh[jj] + b_hh[jj];
    float hz = gh[HH + jj] + b_hh[HH + jj];
    float hn = gh[2 * HH + jj] + b_hh[2 * HH + jj];
    float h = (layer ? w2_cur : w1_cur)[jj];
    float r = 1.0f / (1.0f + expf(-(xr + hr)));
    float z = 1.0f / (1.0f + expf(-(xz + hz)));
    float n = tanhf(xn + r * hn);
    wevo[layer * HH + jj] = (1.0f - z) * n + z * h;
}

// ---------------- node GEMM: out[r][:] = pre(in[r][:]) @ w ----------------
// mode 0: v = in * rs_out[r]                          (conv1 input scaling)
// mode 1: v = relu(in*rs_in[r] + bias) * rs_out[r]    (conv1 finalize + relu + conv2 scaling)
// In-place safe (in == out): each block reads its 4 rows before the sync, writes after.
__global__ __launch_bounds__(256) void gemm64(
        const float* __restrict__ in, const float* __restrict__ w,
        float* __restrict__ out, const float* __restrict__ rs_out,
        const float* __restrict__ rs_in, const float* __restrict__ bias, int mode) {
    __shared__ float wl[HH];
    __shared__ float xs[4][DD];
    for (int i = threadIdx.x; i < HH; i += 256) wl[i] = w[i];
    int wv = threadIdx.x >> 6, lane = threadIdx.x & 63;
    int r = blockIdx.x * 4 + wv;  // grid = 25000 exactly covers 100000
    float v = in[(size_t)r * DD + lane];
    if (mode) v = fmaxf(fmaf(v, rs_in[r], bias[lane]), 0.0f);
    v *= rs_out[r];
    xs[wv][lane] = v;
    __syncthreads();
    float acc = 0.f;
#pragma unroll
    for (int k = 0; k < DD; ++k) acc = fmaf(xs[wv][k], wl[k * DD + lane], acc);
    out[(size_t)r * DD + lane] = acc;
}

// ---------------- CSR aggregation: one wave per dst node, lane = channel ----------------
// mode 0: write raw agg (consumed by gemm64 mode 1)
// mode 1: write agg * rs_in[r] + bias  (final conv2 output)
__global__ __launch_bounds__(256) void agg_kernel(
        const float* __restrict__ h, const int* __restrict__ ssort,
        const int* __restrict__ offs, const float* __restrict__ rs_in,
        const float* __restrict__ bias, float* __restrict__ outp, int mode) {
    int wv = threadIdx.x >> 6, lane = threadIdx.x & 63;
    int r = blockIdx.x * 4 + wv;  // grid = 25000 exactly covers 100000
    int start = offs[r], end = offs[r + 1];
    float acc = 0.f;
    int e = start;
    while (e < end) {
        int cnt = min(end - e, 64);
        int s = (lane < cnt) ? ssort[e + lane] : 0;
        for (int i = 0; i < cnt; ++i) {
            int si = __shfl(s, i);
            acc += h[(size_t)si * DD + lane];
        }
        e += cnt;
    }
    if (mode) acc = fmaf(acc, rs_in[r], bias[lane]);
    outp[(size_t)r * DD + lane] = acc;
}

extern "C" void kernel_launch(void* const* d_in, const int* in_sizes, int n_in,
                              void* d_out, int out_size, void* d_ws, size_t ws_size,
                              hipStream_t stream) {
    const float* node_emb   = (const float*)d_in[0];
    const int*   src        = (const int*)d_in[1];
    const int*   dst        = (const int*)d_in[2];
    const float* gc1_weight = (const float*)d_in[3];
    const float* gc1_bias   = (const float*)d_in[4];
    const float* gc2_weight = (const float*)d_in[5];
    const float* gc2_bias   = (const float*)d_in[6];
    const float* gc1_hist   = (const float*)d_in[7];
    const float* gc2_hist   = (const float*)d_in[8];
    const float* w_ih       = (const float*)d_in[9];
    const float* w_hh       = (const float*)d_in[10];
    const float* b_ih       = (const float*)d_in[11];
    const float* b_hh       = (const float*)d_in[12];
    float* out = (float*)d_out;

    float* ws     = (float*)d_ws;
    float* rs_out = ws;                    // N_NODES
    float* rs_in  = ws + N_NODES;          // N_NODES
    float* gbuf   = ws + 2 * N_NODES;      // 4*H3 = 49152
    float* wevo   = gbuf + 4 * H3;         // 2*HH = 8192 (w1, then w2)
    float* agg    = wevo + 2 * HH;         // N_NODES*DD = 6.4M floats
    int*   hs     = (int*)(agg + (size_t)N_NODES * DD);  // N_NODES (src degree)
    int*   hd     = hs + N_NODES;          // N_NODES (dst degree)
    int*   offs   = hd + N_NODES;          // N_NODES + 1
    int*   cursor = offs + N_NODES + 1;    // N_NODES
    int*   bsum   = cursor + N_NODES;      // 128
    int*   ssort  = bsum + 128;            // N_EDGES

    // ---- build CSR by dst + degrees (sorted once, used by both convs) ----
    zero_i4<<<(2 * N_NODES / 4 + 255) / 256, 256, 0, stream>>>((int4*)hs, 2 * N_NODES / 4);
    hist_kernel<<<2048, 256, 0, stream>>>(src, dst, hs, hd);
    rsqrt_from_hist<<<(N_NODES + 255) / 256, 256, 0, stream>>>(hs, hd, rs_out, rs_in);
    scan1<<<NB_SCAN, 256, 0, stream>>>(hd, offs, bsum);
    scan2<<<1, 64, 0, stream>>>(bsum);
    scan3<<<(N_NODES + 256) / 256, 256, 0, stream>>>(offs, bsum, cursor);
    reorder_kernel<<<(N_EDGES + 255) / 256, 256, 0, stream>>>(src, dst, cursor, ssort);

    // ---- weight evolution (two GRU cells fused: shared w_ih/w_hh read) ----
    gru_matvec<<<6144, 256, 0, stream>>>(w_ih, w_hh, gc1_hist, gc2_hist,
                                         gc1_weight, gc2_weight, gbuf);
    gru_combine<<<32, 256, 0, stream>>>(gbuf, b_ih, b_hh, gc1_weight, gc2_weight, wevo);

    // ---- conv1: h1 = (x * rs_out) @ w1 ; agg1 = segsum(h1[src] by dst) ----
    gemm64<<<25000, 256, 0, stream>>>(node_emb, wevo, out, rs_out, rs_in, gc1_bias, 0);
    agg_kernel<<<25000, 256, 0, stream>>>(out, ssort, offs, rs_in, gc1_bias, agg, 0);

    // ---- conv2: h2 = (relu(agg1*rs_in+b1) * rs_out) @ w2 (in-place in agg) ----
    gemm64<<<25000, 256, 0, stream>>>(agg, wevo + HH, agg, rs_out, rs_in, gc1_bias, 1);
    // ---- agg2 + final bias/scale straight into d_out ----
    agg_kernel<<<25000, 256, 0, stream>>>(agg, ssort, offs, rs_in, gc2_bias, out, 1);
}

// Round 3
// 795.575 us; speedup vs baseline: 1.4956x; 1.1148x over previous
//
#include <hip/hip_runtime.h>
#include <math.h>

#define N_NODES 100000
#define N_EDGES 1200000
#define DD 64
#define HH 4096
#define H3 12288
#define NB_SCAN 98  // ceil(100000/1024)

// ---------------- zero fill (int4) ----------------
__global__ void zero_i4(int4* __restrict__ p, int n4) {
    int i = blockIdx.x * blockDim.x + threadIdx.x;
    if (i < n4) p[i] = make_int4(0, 0, 0, 0);
}

// ---------------- degree histograms (int atomics, L2-resident) ----------------
__global__ void hist_kernel(const int* __restrict__ src, const int* __restrict__ dst,
                            int* __restrict__ hs, int* __restrict__ hd) {
    int i = blockIdx.x * blockDim.x + threadIdx.x;
    int stride = gridDim.x * blockDim.x;
    for (int e = i; e < N_EDGES; e += stride) {
        atomicAdd(&hs[src[e]], 1);
        atomicAdd(&hd[dst[e]], 1);
    }
}

__global__ void rsqrt_from_hist(const int* __restrict__ hs, const int* __restrict__ hd,
                                float* __restrict__ rs_out, float* __restrict__ rs_in) {
    int i = blockIdx.x * blockDim.x + threadIdx.x;
    if (i < N_NODES) {
        rs_out[i] = rsqrtf(fmaxf((float)hs[i], 1.0f));
        rs_in[i]  = rsqrtf(fmaxf((float)hd[i], 1.0f));
    }
}

// ---------------- exclusive scan of hist_dst -> offsets ----------------
__global__ __launch_bounds__(256) void scan1(const int* __restrict__ hist, int* __restrict__ offs,
                                             int* __restrict__ bsum) {
    __shared__ int wsum[4];
    int b = blockIdx.x;
    int base = b * 1024;
    int t = threadIdx.x;
    int idx = base + t * 4;
    int v0 = 0, v1 = 0, v2 = 0, v3 = 0;
    if (idx + 0 < N_NODES) v0 = hist[idx + 0];
    if (idx + 1 < N_NODES) v1 = hist[idx + 1];
    if (idx + 2 < N_NODES) v2 = hist[idx + 2];
    if (idx + 3 < N_NODES) v3 = hist[idx + 3];
    int s = v0 + v1 + v2 + v3;
    int lane = t & 63, wv = t >> 6;
    int sc = s;
#pragma unroll
    for (int off = 1; off < 64; off <<= 1) {
        int n = __shfl_up(sc, off);
        if (lane >= off) sc += n;
    }
    if (lane == 63) wsum[wv] = sc;
    __syncthreads();
    int wadd = 0;
    for (int i = 0; i < wv; ++i) wadd += wsum[i];
    int excl = wadd + sc - s;
    if (idx + 0 < N_NODES) offs[idx + 0] = excl;
    if (idx + 1 < N_NODES) offs[idx + 1] = excl + v0;
    if (idx + 2 < N_NODES) offs[idx + 2] = excl + v0 + v1;
    if (idx + 3 < N_NODES) offs[idx + 3] = excl + v0 + v1 + v2;
    if (t == 255) bsum[b] = wadd + sc;
}

__global__ void scan2(int* __restrict__ bsum) {
    if (threadIdx.x == 0 && blockIdx.x == 0) {
        int acc = 0;
        for (int i = 0; i < NB_SCAN; ++i) { int v = bsum[i]; bsum[i] = acc; acc += v; }
    }
}

__global__ void scan3(int* __restrict__ offs, const int* __restrict__ bsum,
                      int* __restrict__ cursor) {
    int i = blockIdx.x * blockDim.x + threadIdx.x;
    if (i < N_NODES) {
        int o = offs[i] + bsum[i >> 10];
        offs[i] = o;
        cursor[i] = o;
    } else if (i == N_NODES) {
        offs[N_NODES] = N_EDGES;
    }
}

// ---------------- reorder edges by dst (counting sort payload pass) ----------------
__global__ void reorder_kernel(const int* __restrict__ src, const int* __restrict__ dst,
                               int* __restrict__ cursor, int* __restrict__ ssort) {
    int e = blockIdx.x * blockDim.x + threadIdx.x;
    if (e < N_EDGES) {
        int d = dst[e];
        int p = atomicAdd(&cursor[d], 1);
        ssort[p] = src[e];
    }
}

// ---------------- GRU matvecs ----------------
// blocks 0..3071: w_ih rows (vectors = gc1_hist, gc2_hist)
// blocks 3072..6143: w_hh rows (vectors = gc1_weight, gc2_weight)
// Vectors staged in LDS (block-uniform); M streams from HBM with reg prefetch.
// gbuf layout: [0]=w_ih@x1, [1]=w_ih@x2, [2]=w_hh@h1, [3]=w_hh@h2
__global__ __launch_bounds__(256) void gru_matvec(
        const float* __restrict__ w_ih, const float* __restrict__ w_hh,
        const float* __restrict__ x1, const float* __restrict__ x2,
        const float* __restrict__ h1, const float* __restrict__ h2,
        float* __restrict__ gbuf) {
    __shared__ float4 va_s[1024];  // 16 KB
    __shared__ float4 vb_s[1024];  // 16 KB
    int mat = blockIdx.x >= 3072;
    const float4* vaG = (const float4*)(mat ? h1 : x1);
    const float4* vbG = (const float4*)(mat ? h2 : x2);
    for (int i = threadIdx.x; i < 1024; i += 256) {
        va_s[i] = vaG[i];
        vb_s[i] = vbG[i];
    }
    __syncthreads();
    int wv = threadIdx.x >> 6, lane = threadIdx.x & 63;
    int row = (mat ? blockIdx.x - 3072 : blockIdx.x) * 4 + wv;
    const float4* M = (const float4*)((mat ? w_hh : w_ih) + (size_t)row * HH);
    float acc_a = 0.f, acc_b = 0.f;
    float4 m0 = M[lane];
    float4 m1 = M[lane + 64];
#pragma unroll
    for (int i = 0; i < 8; ++i) {
        float4 n0, n1;
        if (i < 7) {
            n0 = M[lane + (i + 1) * 128];
            n1 = M[lane + (i + 1) * 128 + 64];
        }
        float4 a0 = va_s[lane + i * 128], a1 = va_s[lane + i * 128 + 64];
        float4 b0 = vb_s[lane + i * 128], b1 = vb_s[lane + i * 128 + 64];
        acc_a += m0.x * a0.x + m0.y * a0.y + m0.z * a0.z + m0.w * a0.w
               + m1.x * a1.x + m1.y * a1.y + m1.z * a1.z + m1.w * a1.w;
        acc_b += m0.x * b0.x + m0.y * b0.y + m0.z * b0.z + m0.w * b0.w
               + m1.x * b1.x + m1.y * b1.y + m1.z * b1.z + m1.w * b1.w;
        if (i < 7) { m0 = n0; m1 = n1; }
    }
#pragma unroll
    for (int off = 32; off > 0; off >>= 1) {
        acc_a += __shfl_xor(acc_a, off);
        acc_b += __shfl_xor(acc_b, off);
    }
    if (lane == 0) {
        gbuf[(mat * 2 + 0) * H3 + row] = acc_a;
        gbuf[(mat * 2 + 1) * H3 + row] = acc_b;
    }
}

// ---------------- GRU gate combine ----------------
__global__ void gru_combine(const float* __restrict__ gbuf,
                            const float* __restrict__ b_ih, const float* __restrict__ b_hh,
                            const float* __restrict__ w1_cur, const float* __restrict__ w2_cur,
                            float* __restrict__ wevo) {
    int j = blockIdx.x * blockDim.x + threadIdx.x;  // [0, 8192)
    if (j >= 2 * HH) return;
    int layer = j >> 12;
    int jj = j & (HH - 1);
    const float* gx = gbuf + layer * H3;
    const float* gh = gbuf + (2 + layer) * H3;
    float xr = gx[jj] + b_ih[jj];
    float xz = gx[HH + jj] + b_ih[HH + jj];
    float xn = gx[2 * HH + jj] + b_ih[2 * HH + jj];
    float hr = gh[jj] + b_hh[jj];
    float hz = gh[HH + jj] + b_hh[HH + jj];
    float hn = gh[2 * HH + jj] + b_hh[2 * HH + jj];
    float h = (layer ? w2_cur : w1_cur)[jj];
    float r = 1.0f / (1.0f + expf(-(xr + hr)));
    float z = 1.0f / (1.0f + expf(-(xz + hz)));
    float n = tanhf(xn + r * hn);
    wevo[layer * HH + jj] = (1.0f - z) * n + z * h;
}

// ---------------- conv1 node GEMM: out[r][:] = (in[r][:] * rs_out[r]) @ w ----------------
__global__ __launch_bounds__(256) void gemm64(
        const float* __restrict__ in, const float* __restrict__ w,
        float* __restrict__ out, const float* __restrict__ rs_out) {
    __shared__ float wl[HH];
    __shared__ float xs[4][DD];
    for (int i = threadIdx.x; i < 1024; i += 256) ((float4*)wl)[i] = ((const float4*)w)[i];
    int wv = threadIdx.x >> 6, lane = threadIdx.x & 63;
    int r = blockIdx.x * 4 + wv;  // grid 25000 exactly covers 100000
    float v = in[(size_t)r * DD + lane] * rs_out[r];
    xs[wv][lane] = v;
    __syncthreads();
    float acc = 0.f;
#pragma unroll
    for (int k = 0; k < DD; ++k) acc = fmaf(xs[wv][k], wl[k * DD + lane], acc);
    out[(size_t)r * DD + lane] = acc;
}

// ---------------- conv1 aggregate + relu/scale + @W2 (fused) ----------------
// lane layout: sub = lane>>4 (edge slot, 4 edges/iter), c4 = lane&15 (float4 channel group)
__global__ __launch_bounds__(256) void agg_gemm(
        const float* __restrict__ h, const int* __restrict__ ssort,
        const int* __restrict__ offs, const float* __restrict__ rs_out,
        const float* __restrict__ rs_in, const float* __restrict__ bias,
        const float* __restrict__ w, float* __restrict__ outp) {
    __shared__ float wl[HH];
    __shared__ float xs[4][DD];
    for (int i = threadIdx.x; i < 1024; i += 256) ((float4*)wl)[i] = ((const float4*)w)[i];
    int wv = threadIdx.x >> 6, lane = threadIdx.x & 63;
    int sub = lane >> 4, c4 = lane & 15;
    int r = blockIdx.x * 4 + wv;
    int start = offs[r], end = offs[r + 1];
    float4 acc = make_float4(0.f, 0.f, 0.f, 0.f);
    for (int e = start + sub; e < end; e += 4) {
        int s = ssort[e];
        float4 v = *(const float4*)(h + (size_t)s * DD + c4 * 4);
        acc.x += v.x; acc.y += v.y; acc.z += v.z; acc.w += v.w;
    }
#pragma unroll
    for (int off = 16; off <= 32; off <<= 1) {
        acc.x += __shfl_xor(acc.x, off);
        acc.y += __shfl_xor(acc.y, off);
        acc.z += __shfl_xor(acc.z, off);
        acc.w += __shfl_xor(acc.w, off);
    }
    float ri = rs_in[r], ro = rs_out[r];
    float4 bb = *(const float4*)(bias + c4 * 4);
    if (sub == 0) {
        float4 v;
        v.x = fmaxf(fmaf(acc.x, ri, bb.x), 0.f) * ro;
        v.y = fmaxf(fmaf(acc.y, ri, bb.y), 0.f) * ro;
        v.z = fmaxf(fmaf(acc.z, ri, bb.z), 0.f) * ro;
        v.w = fmaxf(fmaf(acc.w, ri, bb.w), 0.f) * ro;
        *(float4*)(&xs[wv][c4 * 4]) = v;
    }
    __syncthreads();
    float o = 0.f;
#pragma unroll
    for (int k = 0; k < DD; ++k) o = fmaf(xs[wv][k], wl[k * DD + lane], o);
    outp[(size_t)r * DD + lane] = o;
}

// ---------------- conv2 aggregate + final bias/scale ----------------
__global__ __launch_bounds__(256) void agg_final(
        const float* __restrict__ h, const int* __restrict__ ssort,
        const int* __restrict__ offs, const float* __restrict__ rs_in,
        const float* __restrict__ bias, float* __restrict__ outp) {
    int wv = threadIdx.x >> 6, lane = threadIdx.x & 63;
    int sub = lane >> 4, c4 = lane & 15;
    int r = blockIdx.x * 4 + wv;
    int start = offs[r], end = offs[r + 1];
    float4 acc = make_float4(0.f, 0.f, 0.f, 0.f);
    for (int e = start + sub; e < end; e += 4) {
        int s = ssort[e];
        float4 v = *(const float4*)(h + (size_t)s * DD + c4 * 4);
        acc.x += v.x; acc.y += v.y; acc.z += v.z; acc.w += v.w;
    }
#pragma unroll
    for (int off = 16; off <= 32; off <<= 1) {
        acc.x += __shfl_xor(acc.x, off);
        acc.y += __shfl_xor(acc.y, off);
        acc.z += __shfl_xor(acc.z, off);
        acc.w += __shfl_xor(acc.w, off);
    }
    if (sub == 0) {
        float ri = rs_in[r];
        float4 bb = *(const float4*)(bias + c4 * 4);
        float4 v;
        v.x = fmaf(acc.x, ri, bb.x);
        v.y = fmaf(acc.y, ri, bb.y);
        v.z = fmaf(acc.z, ri, bb.z);
        v.w = fmaf(acc.w, ri, bb.w);
        *(float4*)(outp + (size_t)r * DD + c4 * 4) = v;
    }
}

extern "C" void kernel_launch(void* const* d_in, const int* in_sizes, int n_in,
                              void* d_out, int out_size, void* d_ws, size_t ws_size,
                              hipStream_t stream) {
    const float* node_emb   = (const float*)d_in[0];
    const int*   src        = (const int*)d_in[1];
    const int*   dst        = (const int*)d_in[2];
    const float* gc1_weight = (const float*)d_in[3];
    const float* gc1_bias   = (const float*)d_in[4];
    const float* gc2_weight = (const float*)d_in[5];
    const float* gc2_bias   = (const float*)d_in[6];
    const float* gc1_hist   = (const float*)d_in[7];
    const float* gc2_hist   = (const float*)d_in[8];
    const float* w_ih       = (const float*)d_in[9];
    const float* w_hh       = (const float*)d_in[10];
    const float* b_ih       = (const float*)d_in[11];
    const float* b_hh       = (const float*)d_in[12];
    float* out = (float*)d_out;

    float* ws     = (float*)d_ws;
    float* rs_out = ws;                    // N_NODES
    float* rs_in  = ws + N_NODES;          // N_NODES
    float* gbuf   = ws + 2 * N_NODES;      // 4*H3
    float* wevo   = gbuf + 4 * H3;         // 2*HH (w1, then w2)
    float* agg    = wevo + 2 * HH;         // N_NODES*DD (h2 staging)
    int*   hs     = (int*)(agg + (size_t)N_NODES * DD);  // N_NODES
    int*   hd     = hs + N_NODES;          // N_NODES
    int*   offs   = hd + N_NODES;          // N_NODES + 1
    int*   cursor = offs + N_NODES + 1;    // N_NODES
    int*   bsum   = cursor + N_NODES;      // 128
    int*   ssort  = bsum + 128;            // N_EDGES

    // ---- build CSR by dst + degrees (sorted once, used by both convs) ----
    zero_i4<<<(2 * N_NODES / 4 + 255) / 256, 256, 0, stream>>>((int4*)hs, 2 * N_NODES / 4);
    hist_kernel<<<2048, 256, 0, stream>>>(src, dst, hs, hd);
    rsqrt_from_hist<<<(N_NODES + 255) / 256, 256, 0, stream>>>(hs, hd, rs_out, rs_in);
    scan1<<<NB_SCAN, 256, 0, stream>>>(hd, offs, bsum);
    scan2<<<1, 64, 0, stream>>>(bsum);
    scan3<<<(N_NODES + 256) / 256, 256, 0, stream>>>(offs, bsum, cursor);
    reorder_kernel<<<(N_EDGES + 255) / 256, 256, 0, stream>>>(src, dst, cursor, ssort);

    // ---- weight evolution (two GRU cells fused: shared w_ih/w_hh read) ----
    gru_matvec<<<6144, 256, 0, stream>>>(w_ih, w_hh, gc1_hist, gc2_hist,
                                         gc1_weight, gc2_weight, gbuf);
    gru_combine<<<32, 256, 0, stream>>>(gbuf, b_ih, b_hh, gc1_weight, gc2_weight, wevo);

    // ---- conv1 GEMM: h1 = (x * rs_out) @ w1  (h1 in d_out) ----
    gemm64<<<25000, 256, 0, stream>>>(node_emb, wevo, out, rs_out);
    // ---- conv1 agg + relu + conv2 input scale + @w2: h2 (in agg buffer) ----
    agg_gemm<<<25000, 256, 0, stream>>>(out, ssort, offs, rs_out, rs_in, gc1_bias,
                                        wevo + HH, agg);
    // ---- conv2 agg + final bias/scale -> d_out ----
    agg_final<<<25000, 256, 0, stream>>>(agg, ssort, offs, rs_in, gc2_bias, out);
}

// Round 7
// 789.242 us; speedup vs baseline: 1.5076x; 1.0080x over previous
//
#include <hip/hip_runtime.h>
#include <math.h>

#define N_NODES 100000
#define N_EDGES 1200000
#define DD 64
#define HH 4096
#define H3 12288
#define NB_SCAN 98  // ceil(100000/1024)

// ---------------- zero fill (int4) ----------------
__global__ void zero_i4(int4* __restrict__ p, int n4) {
    int i = blockIdx.x * blockDim.x + threadIdx.x;
    if (i < n4) p[i] = make_int4(0, 0, 0, 0);
}

// ---------------- degree histograms (int atomics, L2-resident) ----------------
__global__ void hist_kernel(const int* __restrict__ src, const int* __restrict__ dst,
                            int* __restrict__ hs, int* __restrict__ hd) {
    int i = blockIdx.x * blockDim.x + threadIdx.x;
    int stride = gridDim.x * blockDim.x;
    for (int e = i; e < N_EDGES; e += stride) {
        atomicAdd(&hs[src[e]], 1);
        atomicAdd(&hd[dst[e]], 1);
    }
}

__global__ void rsqrt_from_hist(const int* __restrict__ hs, const int* __restrict__ hd,
                                float* __restrict__ rs_out, float* __restrict__ rs_in) {
    int i = blockIdx.x * blockDim.x + threadIdx.x;
    if (i < N_NODES) {
        rs_out[i] = rsqrtf(fmaxf((float)hs[i], 1.0f));
        rs_in[i]  = rsqrtf(fmaxf((float)hd[i], 1.0f));
    }
}

// ---------------- exclusive scan of hist_dst -> offsets ----------------
__global__ __launch_bounds__(256) void scan1(const int* __restrict__ hist, int* __restrict__ offs,
                                             int* __restrict__ bsum) {
    __shared__ int wsum[4];
    int b = blockIdx.x;
    int base = b * 1024;
    int t = threadIdx.x;
    int idx = base + t * 4;
    int v0 = 0, v1 = 0, v2 = 0, v3 = 0;
    if (idx + 0 < N_NODES) v0 = hist[idx + 0];
    if (idx + 1 < N_NODES) v1 = hist[idx + 1];
    if (idx + 2 < N_NODES) v2 = hist[idx + 2];
    if (idx + 3 < N_NODES) v3 = hist[idx + 3];
    int s = v0 + v1 + v2 + v3;
    int lane = t & 63, wv = t >> 6;
    int sc = s;
#pragma unroll
    for (int off = 1; off < 64; off <<= 1) {
        int n = __shfl_up(sc, off);
        if (lane >= off) sc += n;
    }
    if (lane == 63) wsum[wv] = sc;
    __syncthreads();
    int wadd = 0;
    for (int i = 0; i < wv; ++i) wadd += wsum[i];
    int excl = wadd + sc - s;
    if (idx + 0 < N_NODES) offs[idx + 0] = excl;
    if (idx + 1 < N_NODES) offs[idx + 1] = excl + v0;
    if (idx + 2 < N_NODES) offs[idx + 2] = excl + v0 + v1;
    if (idx + 3 < N_NODES) offs[idx + 3] = excl + v0 + v1 + v2;
    if (t == 255) bsum[b] = wadd + sc;
}

__global__ void scan2(int* __restrict__ bsum) {
    if (threadIdx.x == 0 && blockIdx.x == 0) {
        int acc = 0;
        for (int i = 0; i < NB_SCAN; ++i) { int v = bsum[i]; bsum[i] = acc; acc += v; }
    }
}

__global__ void scan3(int* __restrict__ offs, const int* __restrict__ bsum,
                      int* __restrict__ cursor) {
    int i = blockIdx.x * blockDim.x + threadIdx.x;
    if (i < N_NODES) {
        int o = offs[i] + bsum[i >> 10];
        offs[i] = o;
        cursor[i] = o;
    } else if (i == N_NODES) {
        offs[N_NODES] = N_EDGES;
    }
}

// ---------------- reorder edges by dst (counting sort payload pass) ----------------
__global__ void reorder_kernel(const int* __restrict__ src, const int* __restrict__ dst,
                               int* __restrict__ cursor, int* __restrict__ ssort) {
    int e = blockIdx.x * blockDim.x + threadIdx.x;
    if (e < N_EDGES) {
        int d = dst[e];
        int p = atomicAdd(&cursor[d], 1);
        ssort[p] = src[e];
    }
}

// ---------------- GRU matvecs ----------------
// blocks 0..3071: w_ih rows (vectors = gc1_hist, gc2_hist)
// blocks 3072..6143: w_hh rows (vectors = gc1_weight, gc2_weight)
// One wave per row; ALL 16 row-float4s issued to registers up front (16KB/wave
// in flight) -> memory-level parallelism, not prefetch-depth-1.
// gbuf layout: [0]=w_ih@x1, [1]=w_ih@x2, [2]=w_hh@h1, [3]=w_hh@h2
__global__ __launch_bounds__(256) void gru_matvec(
        const float* __restrict__ w_ih, const float* __restrict__ w_hh,
        const float* __restrict__ x1, const float* __restrict__ x2,
        const float* __restrict__ h1, const float* __restrict__ h2,
        float* __restrict__ gbuf) {
    __shared__ float4 va_s[1024];  // 16 KB
    __shared__ float4 vb_s[1024];  // 16 KB
    int mat = blockIdx.x >= 3072;
    const float4* vaG = (const float4*)(mat ? h1 : x1);
    const float4* vbG = (const float4*)(mat ? h2 : x2);
    for (int i = threadIdx.x; i < 1024; i += 256) {
        va_s[i] = vaG[i];
        vb_s[i] = vbG[i];
    }
    __syncthreads();
    int wv = threadIdx.x >> 6, lane = threadIdx.x & 63;
    int row = (mat ? blockIdx.x - 3072 : blockIdx.x) * 4 + wv;
    const float4* M = (const float4*)((mat ? w_hh : w_ih) + (size_t)row * HH);
    float4 m[16];
#pragma unroll
    for (int i = 0; i < 16; ++i) m[i] = M[lane + i * 64];
    float acc_a = 0.f, acc_b = 0.f;
#pragma unroll
    for (int i = 0; i < 16; ++i) {
        float4 a = va_s[lane + i * 64];
        float4 b = vb_s[lane + i * 64];
        acc_a += m[i].x * a.x + m[i].y * a.y + m[i].z * a.z + m[i].w * a.w;
        acc_b += m[i].x * b.x + m[i].y * b.y + m[i].z * b.z + m[i].w * b.w;
    }
#pragma unroll
    for (int off = 32; off > 0; off >>= 1) {
        acc_a += __shfl_xor(acc_a, off);
        acc_b += __shfl_xor(acc_b, off);
    }
    if (lane == 0) {
        gbuf[(mat * 2 + 0) * H3 + row] = acc_a;
        gbuf[(mat * 2 + 1) * H3 + row] = acc_b;
    }
}

// ---------------- GRU gate combine ----------------
__global__ void gru_combine(const float* __restrict__ gbuf,
                            const float* __restrict__ b_ih, const float* __restrict__ b_hh,
                            const float* __restrict__ w1_cur, const float* __restrict__ w2_cur,
                            float* __restrict__ wevo) {
    int j = blockIdx.x * blockDim.x + threadIdx.x;  // [0, 8192)
    if (j >= 2 * HH) return;
    int layer = j >> 12;
    int jj = j & (HH - 1);
    const float* gx = gbuf + layer * H3;
    const float* gh = gbuf + (2 + layer) * H3;
    float xr = gx[jj] + b_ih[jj];
    float xz = gx[HH + jj] + b_ih[HH + jj];
    float xn = gx[2 * HH + jj] + b_ih[2 * HH + jj];
    float hr = gh[jj] + b_hh[jj];
    float hz = gh[HH + jj] + b_hh[HH + jj];
    float hn = gh[2 * HH + jj] + b_hh[2 * HH + jj];
    float h = (layer ? w2_cur : w1_cur)[jj];
    float r = 1.0f / (1.0f + expf(-(xr + hr)));
    float z = 1.0f / (1.0f + expf(-(xz + hz)));
    float n = tanhf(xn + r * hn);
    wevo[layer * HH + jj] = (1.0f - z) * n + z * h;
}

// ---------------- conv1 node GEMM: out[r][:] = (in[r][:] * rs_out[r]) @ w ----------------
__global__ __launch_bounds__(256) void gemm64(
        const float* __restrict__ in, const float* __restrict__ w,
        float* __restrict__ out, const float* __restrict__ rs_out) {
    __shared__ float wl[HH];
    __shared__ float xs[4][DD];
    for (int i = threadIdx.x; i < 1024; i += 256) ((float4*)wl)[i] = ((const float4*)w)[i];
    int wv = threadIdx.x >> 6, lane = threadIdx.x & 63;
    int r = blockIdx.x * 4 + wv;  // grid 25000 exactly covers 100000
    float v = in[(size_t)r * DD + lane] * rs_out[r];
    xs[wv][lane] = v;
    __syncthreads();
    float acc = 0.f;
#pragma unroll
    for (int k = 0; k < DD; ++k) acc = fmaf(xs[wv][k], wl[k * DD + lane], acc);
    out[(size_t)r * DD + lane] = acc;
}

// ---------------- conv1 aggregate + relu/scale + @W2 (fused) ----------------
// lane layout: sub = lane>>4 (edge slot), c4 = lane&15 (float4 channel group).
// Gather loop unrolled x2: 8 edges in flight per wave.
__global__ __launch_bounds__(256) void agg_gemm(
        const float* __restrict__ h, const int* __restrict__ ssort,
        const int* __restrict__ offs, const float* __restrict__ rs_out,
        const float* __restrict__ rs_in, const float* __restrict__ bias,
        const float* __restrict__ w, float* __restrict__ outp) {
    __shared__ float wl[HH];
    __shared__ float xs[4][DD];
    for (int i = threadIdx.x; i < 1024; i += 256) ((float4*)wl)[i] = ((const float4*)w)[i];
    int wv = threadIdx.x >> 6, lane = threadIdx.x & 63;
    int sub = lane >> 4, c4 = lane & 15;
    int r = blockIdx.x * 4 + wv;
    int start = offs[r], end = offs[r + 1];
    float4 acc0 = make_float4(0.f, 0.f, 0.f, 0.f);
    float4 acc1 = make_float4(0.f, 0.f, 0.f, 0.f);
    int e = start + sub;
    for (; e + 4 < end; e += 8) {
        int s0 = ssort[e];
        int s1 = ssort[e + 4];
        float4 v0 = *(const float4*)(h + (size_t)s0 * DD + c4 * 4);
        float4 v1 = *(const float4*)(h + (size_t)s1 * DD + c4 * 4);
        acc0.x += v0.x; acc0.y += v0.y; acc0.z += v0.z; acc0.w += v0.w;
        acc1.x += v1.x; acc1.y += v1.y; acc1.z += v1.z; acc1.w += v1.w;
    }
    if (e < end) {
        int s0 = ssort[e];
        float4 v0 = *(const float4*)(h + (size_t)s0 * DD + c4 * 4);
        acc0.x += v0.x; acc0.y += v0.y; acc0.z += v0.z; acc0.w += v0.w;
    }
    float4 acc = make_float4(acc0.x + acc1.x, acc0.y + acc1.y,
                             acc0.z + acc1.z, acc0.w + acc1.w);
#pragma unroll
    for (int off = 16; off <= 32; off <<= 1) {
        acc.x += __shfl_xor(acc.x, off);
        acc.y += __shfl_xor(acc.y, off);
        acc.z += __shfl_xor(acc.z, off);
        acc.w += __shfl_xor(acc.w, off);
    }
    float ri = rs_in[r], ro = rs_out[r];
    float4 bb = *(const float4*)(bias + c4 * 4);
    if (sub == 0) {
        float4 v;
        v.x = fmaxf(fmaf(acc.x, ri, bb.x), 0.f) * ro;
        v.y = fmaxf(fmaf(acc.y, ri, bb.y), 0.f) * ro;
        v.z = fmaxf(fmaf(acc.z, ri, bb.z), 0.f) * ro;
        v.w = fmaxf(fmaf(acc.w, ri, bb.w), 0.f) * ro;
        *(float4*)(&xs[wv][c4 * 4]) = v;
    }
    __syncthreads();
    float o = 0.f;
#pragma unroll
    for (int k = 0; k < DD; ++k) o = fmaf(xs[wv][k], wl[k * DD + lane], o);
    outp[(size_t)r * DD + lane] = o;
}

// ---------------- conv2 aggregate + final bias/scale ----------------
__global__ __launch_bounds__(256) void agg_final(
        const float* __restrict__ h, const int* __restrict__ ssort,
        const int* __restrict__ offs, const float* __restrict__ rs_in,
        const float* __restrict__ bias, float* __restrict__ outp) {
    int wv = threadIdx.x >> 6, lane = threadIdx.x & 63;
    int sub = lane >> 4, c4 = lane & 15;
    int r = blockIdx.x * 4 + wv;
    int start = offs[r], end = offs[r + 1];
    float4 acc0 = make_float4(0.f, 0.f, 0.f, 0.f);
    float4 acc1 = make_float4(0.f, 0.f, 0.f, 0.f);
    int e = start + sub;
    for (; e + 4 < end; e += 8) {
        int s0 = ssort[e];
        int s1 = ssort[e + 4];
        float4 v0 = *(const float4*)(h + (size_t)s0 * DD + c4 * 4);
        float4 v1 = *(const float4*)(h + (size_t)s1 * DD + c4 * 4);
        acc0.x += v0.x; acc0.y += v0.y; acc0.z += v0.z; acc0.w += v0.w;
        acc1.x += v1.x; acc1.y += v1.y; acc1.z += v1.z; acc1.w += v1.w;
    }
    if (e < end) {
        int s0 = ssort[e];
        float4 v0 = *(const float4*)(h + (size_t)s0 * DD + c4 * 4);
        acc0.x += v0.x; acc0.y += v0.y; acc0.z += v0.z; acc0.w += v0.w;
    }
    float4 acc = make_float4(acc0.x + acc1.x, acc0.y + acc1.y,
                             acc0.z + acc1.z, acc0.w + acc1.w);
#pragma unroll
    for (int off = 16; off <= 32; off <<= 1) {
        acc.x += __shfl_xor(acc.x, off);
        acc.y += __shfl_xor(acc.y, off);
        acc.z += __shfl_xor(acc.z, off);
        acc.w += __shfl_xor(acc.w, off);
    }
    if (sub == 0) {
        float ri = rs_in[r];
        float4 bb = *(const float4*)(bias + c4 * 4);
        float4 v;
        v.x = fmaf(acc.x, ri, bb.x);
        v.y = fmaf(acc.y, ri, bb.y);
        v.z = fmaf(acc.z, ri, bb.z);
        v.w = fmaf(acc.w, ri, bb.w);
        *(float4*)(outp + (size_t)r * DD + c4 * 4) = v;
    }
}

extern "C" void kernel_launch(void* const* d_in, const int* in_sizes, int n_in,
                              void* d_out, int out_size, void* d_ws, size_t ws_size,
                              hipStream_t stream) {
    const float* node_emb   = (const float*)d_in[0];
    const int*   src        = (const int*)d_in[1];
    const int*   dst        = (const int*)d_in[2];
    const float* gc1_weight = (const float*)d_in[3];
    const float* gc1_bias   = (const float*)d_in[4];
    const float* gc2_weight = (const float*)d_in[5];
    const float* gc2_bias   = (const float*)d_in[6];
    const float* gc1_hist   = (const float*)d_in[7];
    const float* gc2_hist   = (const float*)d_in[8];
    const float* w_ih       = (const float*)d_in[9];
    const float* w_hh       = (const float*)d_in[10];
    const float* b_ih       = (const float*)d_in[11];
    const float* b_hh       = (const float*)d_in[12];
    float* out = (float*)d_out;

    float* ws     = (float*)d_ws;
    float* rs_out = ws;                    // N_NODES
    float* rs_in  = ws + N_NODES;          // N_NODES
    float* gbuf   = ws + 2 * N_NODES;      // 4*H3
    float* wevo   = gbuf + 4 * H3;         // 2*HH (w1, then w2)
    float* agg    = wevo + 2 * HH;         // N_NODES*DD (h2 staging)
    int*   hs     = (int*)(agg + (size_t)N_NODES * DD);  // N_NODES
    int*   hd     = hs + N_NODES;          // N_NODES
    int*   offs   = hd + N_NODES;          // N_NODES + 1
    int*   cursor = offs + N_NODES + 1;    // N_NODES
    int*   bsum   = cursor + N_NODES;      // 128
    int*   ssort  = bsum + 128;            // N_EDGES

    // ---- build CSR by dst + degrees (sorted once, used by both convs) ----
    zero_i4<<<(2 * N_NODES / 4 + 255) / 256, 256, 0, stream>>>((int4*)hs, 2 * N_NODES / 4);
    hist_kernel<<<2048, 256, 0, stream>>>(src, dst, hs, hd);
    rsqrt_from_hist<<<(N_NODES + 255) / 256, 256, 0, stream>>>(hs, hd, rs_out, rs_in);
    scan1<<<NB_SCAN, 256, 0, stream>>>(hd, offs, bsum);
    scan2<<<1, 64, 0, stream>>>(bsum);
    scan3<<<(N_NODES + 256) / 256, 256, 0, stream>>>(offs, bsum, cursor);
    reorder_kernel<<<(N_EDGES + 255) / 256, 256, 0, stream>>>(src, dst, cursor, ssort);

    // ---- weight evolution (two GRU cells fused: shared w_ih/w_hh read) ----
    gru_matvec<<<6144, 256, 0, stream>>>(w_ih, w_hh, gc1_hist, gc2_hist,
                                         gc1_weight, gc2_weight, gbuf);
    gru_combine<<<32, 256, 0, stream>>>(gbuf, b_ih, b_hh, gc1_weight, gc2_weight, wevo);

    // ---- conv1 GEMM: h1 = (x * rs_out) @ w1  (h1 in d_out) ----
    gemm64<<<25000, 256, 0, stream>>>(node_emb, wevo, out, rs_out);
    // ---- conv1 agg + relu + conv2 input scale + @w2: h2 (in agg buffer) ----
    agg_gemm<<<25000, 256, 0, stream>>>(out, ssort, offs, rs_out, rs_in, gc1_bias,
                                        wevo + HH, agg);
    // ---- conv2 agg + final bias/scale -> d_out ----
    agg_final<<<25000, 256, 0, stream>>>(agg, ssort, offs, rs_in, gc2_bias, out);
}